// Round 2
// baseline (425.600 us; speedup 1.0000x reference)
//
#include <hip/hip_runtime.h>

typedef unsigned long long ull;

#define NA 147456
#define NB 16
#define NBINS 16384        // top-14 bits of monotonic key
#define CAND_CAP 2048
#define NPOST 1000

// ws layout (bytes)
#define OFF_CAND    0                    // 16*2048*8      = 262144
#define OFF_MASK    262144               // 16*1000*16*8   = 2048000
#define OFF_HIST    2310144              // 16*16384*4     = 1048576
#define OFF_PART    3358720              // 16*16*8        = 2048
#define OFF_META    3360768              // 16*16          = 256
#define OFF_CNT     3361024              // 16*4           = 64
#define OFF_SBOX    3361088              // 16*1000*16     = 256000
#define OFF_SSCORE  3617088              // 16*1000*4      = 64000

__device__ __forceinline__ unsigned mkey(float f) {
  unsigned u = __float_as_uint(f);
  return u ^ ((unsigned)((int)u >> 31) | 0x80000000u);  // monotonic: bigger float -> bigger key
}

// ---------------- K0: zero hist + candidate counters (ws is poisoned 0xAA) ----
__global__ void k_init(unsigned* hist, unsigned* cnt) {
  int n = NB * NBINS;
  for (int i = blockIdx.x * blockDim.x + threadIdx.x; i < n; i += gridDim.x * blockDim.x)
    hist[i] = 0;
  if (blockIdx.x == 0 && threadIdx.x < NB) cnt[threadIdx.x] = 0;
}

// ---------------- K1: fused online softmax-reduce + 14-bit histogram ---------
__global__ __launch_bounds__(256) void k_reduce_hist(const float* __restrict__ labels,
                                                     unsigned* __restrict__ hist,
                                                     float2* __restrict__ partial) {
  int b = blockIdx.x >> 4, blk = blockIdx.x & 15;
  __shared__ unsigned lh[NBINS];           // 64KB
  __shared__ float rm[256], rs[256];
  for (int i = threadIdx.x; i < NBINS; i += 256) lh[i] = 0;
  __syncthreads();

  const float* row = labels + (size_t)b * NA;
  const int chunk = NA / 16;               // 9216, divisible by 256
  int base = blk * chunk;
  float m = -INFINITY, s = 0.f;
  for (int i = threadIdx.x; i < chunk; i += 256) {
    float v = row[base + i];
    atomicAdd(&lh[mkey(v) >> 18], 1u);
    if (v > m) { s = s * expf(m - v) + 1.f; m = v; }
    else       { s += expf(v - m); }
  }
  rm[threadIdx.x] = m; rs[threadIdx.x] = s;
  __syncthreads();
  for (int off = 128; off > 0; off >>= 1) {
    if (threadIdx.x < off) {
      float m1 = rm[threadIdx.x], s1 = rs[threadIdx.x];
      float m2 = rm[threadIdx.x + off], s2 = rs[threadIdx.x + off];
      float M = fmaxf(m1, m2);
      rm[threadIdx.x] = M;
      rs[threadIdx.x] = s1 * expf(m1 - M) + s2 * expf(m2 - M);
    }
    __syncthreads();
  }
  if (threadIdx.x == 0) partial[blockIdx.x] = make_float2(rm[0], rs[0]);
  for (int i = threadIdx.x; i < NBINS; i += 256) {
    unsigned c = lh[i];
    if (c) atomicAdd(&hist[b * NBINS + i], c);
  }
}

// ---------------- K2: finalize (m,S), find threshold bin ---------------------
__global__ __launch_bounds__(1024) void k_threshold(const unsigned* __restrict__ hist,
                                                    const float2* __restrict__ partial,
                                                    float4* __restrict__ meta) {
  int b = blockIdx.x;
  __shared__ float red_m, red_s;
  __shared__ unsigned cs[1024];
  if (threadIdx.x == 0) {
    float m = -INFINITY, s = 0.f;
    for (int i = 0; i < 16; ++i) {
      float2 p = partial[b * 16 + i];
      float M = fmaxf(m, p.x);
      s = s * expf(m - M) + p.y * expf(p.x - M);
      m = M;
    }
    red_m = m; red_s = s;
  }
  const unsigned* h = hist + (size_t)b * NBINS;
  int t = threadIdx.x;
  unsigned local[16], lsum = 0;
  for (int q = 0; q < 16; ++q) {            // rank r = t*16+q, bin = NBINS-1-r (scan from top)
    local[q] = h[NBINS - 1 - (t * 16 + q)];
    lsum += local[q];
  }
  cs[t] = lsum;
  __syncthreads();
  for (int off = 1; off < 1024; off <<= 1) {  // Hillis-Steele inclusive scan
    unsigned v = (t >= off) ? cs[t - off] : 0u;
    __syncthreads();
    cs[t] += v;
    __syncthreads();
  }
  unsigned incl = cs[t], excl = incl - lsum;
  if (excl < NPOST && incl >= NPOST) {
    unsigned running = excl;
    for (int q = 0; q < 16; ++q) {
      unsigned c = local[q];
      if (running < NPOST && running + c >= NPOST) {
        unsigned bin = NBINS - 1 - (t * 16 + q);
        meta[b] = make_float4(red_m, red_s, __uint_as_float(bin), 0.f);
      }
      running += c;
    }
  }
}

// ---------------- K3: compact candidates >= threshold bin --------------------
__global__ __launch_bounds__(256) void k_compact(const float* __restrict__ labels,
                                                 const float4* __restrict__ meta,
                                                 ull* __restrict__ cand,
                                                 unsigned* __restrict__ cnt) {
  int b = blockIdx.x >> 4, blk = blockIdx.x & 15;
  unsigned tb = __float_as_uint(meta[b].z);
  const float* row = labels + (size_t)b * NA;
  const int chunk = NA / 16;
  int base = blk * chunk;
  for (int i = threadIdx.x; i < chunk; i += 256) {
    int idx = base + i;
    unsigned k = mkey(row[idx]);
    if ((k >> 18) >= tb) {
      unsigned p = atomicAdd(&cnt[b], 1u);
      if (p < CAND_CAP) cand[(size_t)b * CAND_CAP + p] = ((ull)k << 32) | (unsigned)~idx;
    }
  }
}

// ---------------- K4: bitonic sort candidates, emit top-1000 boxes/scores ----
__global__ __launch_bounds__(1024) void k_sort_emit(const ull* __restrict__ cand,
                                                    const unsigned* __restrict__ cnt,
                                                    const float4* __restrict__ meta,
                                                    const float* __restrict__ labels,
                                                    const float* __restrict__ deltas,
                                                    const float4* __restrict__ anchors,
                                                    const float* __restrict__ variances,
                                                    float4* __restrict__ sboxes,
                                                    float* __restrict__ sscores) {
  int b = blockIdx.x;
  __shared__ ull sd[CAND_CAP];
  unsigned n = cnt[b]; if (n > CAND_CAP) n = CAND_CAP;
  for (int i = threadIdx.x; i < CAND_CAP; i += 1024)
    sd[i] = (i < (int)n) ? cand[(size_t)b * CAND_CAP + i] : 0ULL;

  // bitonic sort, descending (key desc, index asc via ~idx in low bits)
  for (int k = 2; k <= CAND_CAP; k <<= 1) {
    for (int j = k >> 1; j > 0; j >>= 1) {
      __syncthreads();
      for (int e = threadIdx.x; e < CAND_CAP; e += 1024) {
        int x = e ^ j;
        if (x > e) {
          ull a = sd[e], c = sd[x];
          bool up = (e & k) == 0;
          if (up ? (a < c) : (a > c)) { sd[e] = c; sd[x] = a; }
        }
      }
    }
  }
  __syncthreads();

  int r = threadIdx.x;
  if (r < NPOST) {
    ull en = sd[r];
    unsigned idx = ~(unsigned)(en & 0xFFFFFFFFu);
    float4 mt = meta[b];
    float lab = labels[(size_t)b * NA + idx];
    float score = expf(lab - mt.x) / mt.y;

    float4 an = anchors[idx];                     // [y1,x1,y2,x2]
    float aw = an.w - an.y;
    float ah = an.z - an.x;
    float acx = an.y + 0.5f * aw;
    float acy = an.x + 0.5f * ah;
    float4 dl = *(const float4*)(deltas + ((size_t)b * NA + idx) * 4);
    float4 var = *(const float4*)variances;
    float t0 = dl.x * var.x, t1 = dl.y * var.y, t2 = dl.z * var.z, t3 = dl.w * var.w;
    float bw = expf(t3) * aw;
    float bh = expf(t2) * ah;
    float bcx = t1 * aw + acx;
    float bcy = t0 * ah + acy;
    float y1 = bcy - 0.5f * bh, x1 = bcx - 0.5f * bw;
    float y2 = bh + y1, x2 = bw + x1;
    sboxes[(size_t)b * NPOST + r] = make_float4(y1, x1, y2, x2);
    sscores[(size_t)b * NPOST + r] = score;
  }
}

// ---------------- K5: pairwise IoU suppression bitmask -----------------------
__global__ __launch_bounds__(256) void k_mask(const float4* __restrict__ sboxes,
                                              ull* __restrict__ mask) {
  int b = blockIdx.x / 63, tile = blockIdx.x % 63;
  __shared__ float4 bx[NPOST];               // 16KB
  for (int j = threadIdx.x; j < NPOST; j += 256) bx[j] = sboxes[(size_t)b * NPOST + j];
  __syncthreads();
  int il = threadIdx.x >> 4, w = threadIdx.x & 15;
  int i = tile * 16 + il;
  if (i < NPOST) {
    float4 bi = bx[i];
    float ay1 = bi.x, ax1 = bi.y, ay2 = bi.z, ax2 = bi.w;
    float areai = (ay2 - ay1) * (ax2 - ax1);
    ull bits = 0;
    for (int jj = 0; jj < 64; ++jj) {
      int jb = (jj + w) & 63;                // skew to dodge LDS bank conflicts
      int j = (w << 6) + jb;
      if (j > i && j < NPOST) {
        float4 bj = bx[j];
        float areaj = (bj.z - bj.x) * (bj.w - bj.y);
        float iy1 = fmaxf(ay1, bj.x), ix1 = fmaxf(ax1, bj.y);
        float iy2 = fminf(ay2, bj.z), ix2 = fminf(ax2, bj.w);
        float inter = fmaxf(iy2 - iy1, 0.f) * fmaxf(ix2 - ix1, 0.f);
        float uni = areai + areaj - inter;
        float iou = inter / fmaxf(uni, 1e-9f);
        if (iou > 0.7f) bits |= (1ull << jb);
      }
    }
    mask[((size_t)b * NPOST + i) * 16 + w] = bits;
  }
}

// ---------------- K6: serial greedy NMS + compact/zero output ----------------
__global__ __launch_bounds__(256) void k_nms(const ull* __restrict__ mask,
                                             const float4* __restrict__ sboxes,
                                             const float* __restrict__ sscores,
                                             float* __restrict__ out) {
  int b = blockIdx.x;
  __shared__ unsigned char keep[NPOST];
  __shared__ short posA[NPOST];
  __shared__ int totalS;
  int tid = threadIdx.x;
  if (tid < 64) {                            // single wave does the serial scan
    int lane = tid;
    const ull* Mrow = mask + (size_t)b * NPOST * 16;
    ull remv = 0;
    ull buf[8];                              // 8-deep statically-indexed prefetch ring
#pragma unroll
    for (int d = 0; d < 8; ++d) {
      ull v = 0;
      if (lane < 16) v = Mrow[d * 16 + lane];
      buf[d] = v;
    }
    int cnt = 0;
    for (int i0 = 0; i0 < NPOST; i0 += 8) {
#pragma unroll
      for (int d = 0; d < 8; ++d) {
        int i = i0 + d;
        ull cur = buf[d];
        {
          ull v = 0;
          int nx = i + 8;
          if (nx < NPOST && lane < 16) v = Mrow[nx * 16 + lane];
          buf[d] = v;
        }
        int w = i >> 6, bit = i & 63;
        ull rw = __shfl(remv, w);
        if (!((rw >> bit) & 1ull)) {
          if (lane < 16) remv |= cur;
          if (lane == 0) { keep[i] = 1; posA[i] = (short)cnt; }
          cnt++;
        } else if (lane == 0) {
          keep[i] = 0;
        }
      }
    }
    if (lane == 0) totalS = cnt;
  }
  __syncthreads();
  int total = totalS;
  float4* ob = (float4*)out;                 // boxes: 16*1000 float4
  float* os = out + (size_t)NB * NPOST * 4;  // scores: 16*1000 floats
  for (int r = tid; r < NPOST; r += 256) {
    if (r >= total) {
      ob[(size_t)b * NPOST + r] = make_float4(0.f, 0.f, 0.f, 0.f);
      os[(size_t)b * NPOST + r] = 0.f;
    }
  }
  for (int r = tid; r < NPOST; r += 256) {
    if (keep[r]) {
      int p = posA[r];
      ob[(size_t)b * NPOST + p] = sboxes[(size_t)b * NPOST + r];
      os[(size_t)b * NPOST + p] = sscores[(size_t)b * NPOST + r];
    }
  }
}

extern "C" void kernel_launch(void* const* d_in, const int* in_sizes, int n_in,
                              void* d_out, int out_size, void* d_ws, size_t ws_size,
                              hipStream_t stream) {
  const float* deltas    = (const float*)d_in[0];
  const float* labels    = (const float*)d_in[1];
  const float* anchors   = (const float*)d_in[2];
  const float* variances = (const float*)d_in[3];

  char* ws = (char*)d_ws;
  ull*      cand    = (ull*)(ws + OFF_CAND);
  ull*      mask    = (ull*)(ws + OFF_MASK);
  unsigned* hist    = (unsigned*)(ws + OFF_HIST);
  float2*   partial = (float2*)(ws + OFF_PART);
  float4*   meta    = (float4*)(ws + OFF_META);
  unsigned* cnt     = (unsigned*)(ws + OFF_CNT);
  float4*   sboxes  = (float4*)(ws + OFF_SBOX);
  float*    sscores = (float*)(ws + OFF_SSCORE);

  k_init<<<256, 256, 0, stream>>>(hist, cnt);
  k_reduce_hist<<<NB * 16, 256, 0, stream>>>(labels, hist, partial);
  k_threshold<<<NB, 1024, 0, stream>>>(hist, partial, meta);
  k_compact<<<NB * 16, 256, 0, stream>>>(labels, meta, cand, cnt);
  k_sort_emit<<<NB, 1024, 0, stream>>>(cand, cnt, meta, labels, deltas,
                                       (const float4*)anchors, variances,
                                       sboxes, sscores);
  k_mask<<<NB * 63, 256, 0, stream>>>(sboxes, mask);
  k_nms<<<NB, 256, 0, stream>>>(mask, sboxes, sscores, (float*)d_out);
}

// Round 3
// 304.080 us; speedup vs baseline: 1.3996x; 1.3996x over previous
//
#include <hip/hip_runtime.h>

typedef unsigned long long ull;

#define NA 147456
#define NB 16
#define NBINS 16384        // top-14 bits of monotonic key
#define CAND_CAP 2048
#define NPOST 1000

// ws layout (bytes)
#define OFF_CAND    0                    // 16*2048*8      = 262144
#define OFF_MASK    262144               // 16*1000*16*8   = 2048000
#define OFF_HIST    2310144              // 16*16384*4     = 1048576
#define OFF_PART    3358720              // 16*16*8        = 2048
#define OFF_META    3360768              // 16*16          = 256
#define OFF_CNT     3361024              // 16*4           = 64
#define OFF_SBOX    3361088              // 16*1000*16     = 256000
#define OFF_SSCORE  3617088              // 16*1000*4      = 64000

__device__ __forceinline__ unsigned mkey(float f) {
  unsigned u = __float_as_uint(f);
  return u ^ ((unsigned)((int)u >> 31) | 0x80000000u);  // monotonic: bigger float -> bigger key
}

__device__ __forceinline__ ull readlane64(ull v, int lane) {
  unsigned lo = (unsigned)__builtin_amdgcn_readlane((int)(unsigned)(v & 0xFFFFFFFFu), lane);
  unsigned hi = (unsigned)__builtin_amdgcn_readlane((int)(unsigned)(v >> 32), lane);
  return ((ull)hi << 32) | lo;
}

// ---------------- K0: zero hist + candidate counters (ws is poisoned 0xAA) ----
__global__ void k_init(unsigned* hist, unsigned* cnt) {
  int n = NB * NBINS;
  for (int i = blockIdx.x * blockDim.x + threadIdx.x; i < n; i += gridDim.x * blockDim.x)
    hist[i] = 0;
  if (blockIdx.x == 0 && threadIdx.x < NB) cnt[threadIdx.x] = 0;
}

// ---------------- K1: fused online softmax-reduce + 14-bit histogram ---------
__global__ __launch_bounds__(256) void k_reduce_hist(const float* __restrict__ labels,
                                                     unsigned* __restrict__ hist,
                                                     float2* __restrict__ partial) {
  int b = blockIdx.x >> 4, blk = blockIdx.x & 15;
  __shared__ unsigned lh[NBINS];           // 64KB
  __shared__ float rm[256], rs[256];
  for (int i = threadIdx.x; i < NBINS; i += 256) lh[i] = 0;
  __syncthreads();

  const float* row = labels + (size_t)b * NA;
  const int chunk = NA / 16;               // 9216, divisible by 256
  int base = blk * chunk;
  float m = -INFINITY, s = 0.f;
  for (int i = threadIdx.x; i < chunk; i += 256) {
    float v = row[base + i];
    atomicAdd(&lh[mkey(v) >> 18], 1u);
    if (v > m) { s = s * expf(m - v) + 1.f; m = v; }
    else       { s += expf(v - m); }
  }
  rm[threadIdx.x] = m; rs[threadIdx.x] = s;
  __syncthreads();
  for (int off = 128; off > 0; off >>= 1) {
    if (threadIdx.x < off) {
      float m1 = rm[threadIdx.x], s1 = rs[threadIdx.x];
      float m2 = rm[threadIdx.x + off], s2 = rs[threadIdx.x + off];
      float M = fmaxf(m1, m2);
      rm[threadIdx.x] = M;
      rs[threadIdx.x] = s1 * expf(m1 - M) + s2 * expf(m2 - M);
    }
    __syncthreads();
  }
  if (threadIdx.x == 0) partial[blockIdx.x] = make_float2(rm[0], rs[0]);
  for (int i = threadIdx.x; i < NBINS; i += 256) {
    unsigned c = lh[i];
    if (c) atomicAdd(&hist[b * NBINS + i], c);
  }
}

// ---------------- K2: finalize (m,S), find threshold bin ---------------------
__global__ __launch_bounds__(1024) void k_threshold(const unsigned* __restrict__ hist,
                                                    const float2* __restrict__ partial,
                                                    float4* __restrict__ meta) {
  int b = blockIdx.x;
  __shared__ float red_m, red_s;
  __shared__ unsigned cs[1024];
  if (threadIdx.x == 0) {
    float m = -INFINITY, s = 0.f;
    for (int i = 0; i < 16; ++i) {
      float2 p = partial[b * 16 + i];
      float M = fmaxf(m, p.x);
      s = s * expf(m - M) + p.y * expf(p.x - M);
      m = M;
    }
    red_m = m; red_s = s;
  }
  const unsigned* h = hist + (size_t)b * NBINS;
  int t = threadIdx.x;
  unsigned local[16], lsum = 0;
  for (int q = 0; q < 16; ++q) {            // rank r = t*16+q, bin = NBINS-1-r (scan from top)
    local[q] = h[NBINS - 1 - (t * 16 + q)];
    lsum += local[q];
  }
  cs[t] = lsum;
  __syncthreads();
  for (int off = 1; off < 1024; off <<= 1) {  // Hillis-Steele inclusive scan
    unsigned v = (t >= off) ? cs[t - off] : 0u;
    __syncthreads();
    cs[t] += v;
    __syncthreads();
  }
  unsigned incl = cs[t], excl = incl - lsum;
  if (excl < NPOST && incl >= NPOST) {
    unsigned running = excl;
    for (int q = 0; q < 16; ++q) {
      unsigned c = local[q];
      if (running < NPOST && running + c >= NPOST) {
        unsigned bin = NBINS - 1 - (t * 16 + q);
        meta[b] = make_float4(red_m, red_s, __uint_as_float(bin), 0.f);
      }
      running += c;
    }
  }
}

// ---------------- K3: compact candidates >= threshold bin --------------------
__global__ __launch_bounds__(256) void k_compact(const float* __restrict__ labels,
                                                 const float4* __restrict__ meta,
                                                 ull* __restrict__ cand,
                                                 unsigned* __restrict__ cnt) {
  int b = blockIdx.x >> 4, blk = blockIdx.x & 15;
  unsigned tb = __float_as_uint(meta[b].z);
  const float* row = labels + (size_t)b * NA;
  const int chunk = NA / 16;
  int base = blk * chunk;
  for (int i = threadIdx.x; i < chunk; i += 256) {
    int idx = base + i;
    unsigned k = mkey(row[idx]);
    if ((k >> 18) >= tb) {
      unsigned p = atomicAdd(&cnt[b], 1u);
      if (p < CAND_CAP) cand[(size_t)b * CAND_CAP + p] = ((ull)k << 32) | (unsigned)~idx;
    }
  }
}

// ---------------- K4: bitonic sort candidates, emit top-1000 boxes/scores ----
__global__ __launch_bounds__(1024) void k_sort_emit(const ull* __restrict__ cand,
                                                    const unsigned* __restrict__ cnt,
                                                    const float4* __restrict__ meta,
                                                    const float* __restrict__ labels,
                                                    const float* __restrict__ deltas,
                                                    const float4* __restrict__ anchors,
                                                    const float* __restrict__ variances,
                                                    float4* __restrict__ sboxes,
                                                    float* __restrict__ sscores) {
  int b = blockIdx.x;
  __shared__ ull sd[CAND_CAP];
  unsigned n = cnt[b]; if (n > CAND_CAP) n = CAND_CAP;
  for (int i = threadIdx.x; i < CAND_CAP; i += 1024)
    sd[i] = (i < (int)n) ? cand[(size_t)b * CAND_CAP + i] : 0ULL;

  // bitonic sort, descending (key desc, index asc via ~idx in low bits)
  for (int k = 2; k <= CAND_CAP; k <<= 1) {
    for (int j = k >> 1; j > 0; j >>= 1) {
      __syncthreads();
      for (int e = threadIdx.x; e < CAND_CAP; e += 1024) {
        int x = e ^ j;
        if (x > e) {
          ull a = sd[e], c = sd[x];
          bool up = (e & k) == 0;
          if (up ? (a < c) : (a > c)) { sd[e] = c; sd[x] = a; }
        }
      }
    }
  }
  __syncthreads();

  int r = threadIdx.x;
  if (r < NPOST) {
    ull en = sd[r];
    unsigned idx = ~(unsigned)(en & 0xFFFFFFFFu);
    float4 mt = meta[b];
    float lab = labels[(size_t)b * NA + idx];
    float score = expf(lab - mt.x) / mt.y;

    float4 an = anchors[idx];                     // [y1,x1,y2,x2]
    float aw = an.w - an.y;
    float ah = an.z - an.x;
    float acx = an.y + 0.5f * aw;
    float acy = an.x + 0.5f * ah;
    float4 dl = *(const float4*)(deltas + ((size_t)b * NA + idx) * 4);
    float4 var = *(const float4*)variances;
    float t0 = dl.x * var.x, t1 = dl.y * var.y, t2 = dl.z * var.z, t3 = dl.w * var.w;
    float bw = expf(t3) * aw;
    float bh = expf(t2) * ah;
    float bcx = t1 * aw + acx;
    float bcy = t0 * ah + acy;
    float y1 = bcy - 0.5f * bh, x1 = bcx - 0.5f * bw;
    float y2 = bh + y1, x2 = bw + x1;
    sboxes[(size_t)b * NPOST + r] = make_float4(y1, x1, y2, x2);
    sscores[(size_t)b * NPOST + r] = score;
  }
}

// ---------------- K5: pairwise IoU suppression bitmask -----------------------
__global__ __launch_bounds__(256) void k_mask(const float4* __restrict__ sboxes,
                                              ull* __restrict__ mask) {
  int b = blockIdx.x / 63, tile = blockIdx.x % 63;
  __shared__ float4 bx[NPOST];               // 16KB
  for (int j = threadIdx.x; j < NPOST; j += 256) bx[j] = sboxes[(size_t)b * NPOST + j];
  __syncthreads();
  int il = threadIdx.x >> 4, w = threadIdx.x & 15;
  int i = tile * 16 + il;
  if (i < NPOST) {
    float4 bi = bx[i];
    float ay1 = bi.x, ax1 = bi.y, ay2 = bi.z, ax2 = bi.w;
    float areai = (ay2 - ay1) * (ax2 - ax1);
    ull bits = 0;
    for (int jj = 0; jj < 64; ++jj) {
      int jb = (jj + w) & 63;                // skew to dodge LDS bank conflicts
      int j = (w << 6) + jb;
      if (j > i && j < NPOST) {
        float4 bj = bx[j];
        float areaj = (bj.z - bj.x) * (bj.w - bj.y);
        float iy1 = fmaxf(ay1, bj.x), ix1 = fmaxf(ax1, bj.y);
        float iy2 = fminf(ay2, bj.z), ix2 = fminf(ax2, bj.w);
        float inter = fmaxf(iy2 - iy1, 0.f) * fmaxf(ix2 - ix1, 0.f);
        float uni = areai + areaj - inter;
        float iou = inter / fmaxf(uni, 1e-9f);
        if (iou > 0.7f) bits |= (1ull << jb);
      }
    }
    mask[((size_t)b * NPOST + i) * 16 + w] = bits;
  }
}

// ---------------- K6: serial greedy NMS, shfl-free chain ---------------------
// Lane l<16 holds suppression word l in registers; test bit comes from a
// scalar (SGPR) cache of word w=i>>6 refreshed via v_readlane after each keep.
// After word w completes, remv[w] is final and keep bits = ~remv[w].
__global__ __launch_bounds__(256) void k_nms(const ull* __restrict__ mask,
                                             const float4* __restrict__ sboxes,
                                             const float* __restrict__ sscores,
                                             float* __restrict__ out) {
  int b = blockIdx.x;
  __shared__ ull keepw[16];
  __shared__ int pref[17];
  int tid = threadIdx.x;

  if (tid < 64) {
    int lane = tid;
    const ull* Mrow = mask + (size_t)b * NPOST * 16;
    int wsel = lane & 15;
    ull vremv = 0;
    ull buf[32];                             // 32-deep static prefetch ring
#pragma unroll
    for (int d = 0; d < 32; ++d)
      buf[d] = Mrow[(size_t)d * 16 + wsel];

#pragma unroll 1
    for (int w = 0; w < 16; ++w) {
      ull rm = readlane64(vremv, w);
#pragma unroll 1
      for (int b0 = 0; b0 < 64; b0 += 32) {
#pragma unroll
        for (int d = 0; d < 32; ++d) {
          int t = w * 64 + b0 + d;           // scan index (padded to 1024)
          ull cur = buf[d];
          int nx = t + 32;
          int rc = nx < NPOST ? nx : NPOST - 1;  // row 999's mask row is all-zero
          buf[d] = Mrow[(size_t)rc * 16 + wsel];
          int bit = b0 + d;
          if (!((rm >> bit) & 1ull)) {
            vremv |= cur;
            rm = readlane64(vremv, w);
          }
        }
      }
      if (lane == 0) keepw[w] = (w == 15) ? (~rm & ((1ull << 40) - 1)) : ~rm;
    }
    if (lane == 0) {
      int a = 0;
      for (int w = 0; w < 16; ++w) { pref[w] = a; a += __popcll(keepw[w]); }
      pref[16] = a;
    }
  }
  __syncthreads();

  int total = pref[16];
  float4* ob = (float4*)out;                 // boxes: 16*1000 float4
  float* os = out + (size_t)NB * NPOST * 4;  // scores: 16*1000 floats
  for (int r = tid; r < NPOST; r += 256) {
    if (r >= total) {
      ob[(size_t)b * NPOST + r] = make_float4(0.f, 0.f, 0.f, 0.f);
      os[(size_t)b * NPOST + r] = 0.f;
    }
  }
  for (int r = tid; r < NPOST; r += 256) {
    int w = r >> 6, bb = r & 63;
    ull kw = keepw[w];
    if ((kw >> bb) & 1ull) {
      int pos = pref[w] + __popcll(bb ? (kw & ((1ull << bb) - 1)) : 0ull);
      ob[(size_t)b * NPOST + pos] = sboxes[(size_t)b * NPOST + r];
      os[(size_t)b * NPOST + pos] = sscores[(size_t)b * NPOST + r];
    }
  }
}

extern "C" void kernel_launch(void* const* d_in, const int* in_sizes, int n_in,
                              void* d_out, int out_size, void* d_ws, size_t ws_size,
                              hipStream_t stream) {
  const float* deltas    = (const float*)d_in[0];
  const float* labels    = (const float*)d_in[1];
  const float* anchors   = (const float*)d_in[2];
  const float* variances = (const float*)d_in[3];

  char* ws = (char*)d_ws;
  ull*      cand    = (ull*)(ws + OFF_CAND);
  ull*      mask    = (ull*)(ws + OFF_MASK);
  unsigned* hist    = (unsigned*)(ws + OFF_HIST);
  float2*   partial = (float2*)(ws + OFF_PART);
  float4*   meta    = (float4*)(ws + OFF_META);
  unsigned* cnt     = (unsigned*)(ws + OFF_CNT);
  float4*   sboxes  = (float4*)(ws + OFF_SBOX);
  float*    sscores = (float*)(ws + OFF_SSCORE);

  k_init<<<256, 256, 0, stream>>>(hist, cnt);
  k_reduce_hist<<<NB * 16, 256, 0, stream>>>(labels, hist, partial);
  k_threshold<<<NB, 1024, 0, stream>>>(hist, partial, meta);
  k_compact<<<NB * 16, 256, 0, stream>>>(labels, meta, cand, cnt);
  k_sort_emit<<<NB, 1024, 0, stream>>>(cand, cnt, meta, labels, deltas,
                                       (const float4*)anchors, variances,
                                       sboxes, sscores);
  k_mask<<<NB * 63, 256, 0, stream>>>(sboxes, mask);
  k_nms<<<NB, 256, 0, stream>>>(mask, sboxes, sscores, (float*)d_out);
}